// Round 4
// baseline (879.493 us; speedup 1.0000x reference)
//
#include <hip/hip_runtime.h>
#include <math.h>

#define NNODES 50000
#define NEDGES 800000
#define ETOT   850000            // edges + self loops
#define F      64
#define NB     782               // ceil(NNODES/64) buckets of 64 nodes
#define NBLK   256               // staging blocks
#define SITER  13                // edges per thread in staging (256*256*13 >= ETOT)
#define EPB    (256 * SITER)     // 3328 edges per staging block
#define LIN_BLOCKS (NNODES / 16) // 3125
#define ACC_LD 68                // padded LDS row stride (bank spread)

// ---------------------------------------------------------------------------
// Linear body: h = x @ W ; as_ = h.a_src ; ad_ = h.a_dst   (16 nodes / block)
// ---------------------------------------------------------------------------
__device__ __forceinline__ void linear_body(
    const float* __restrict__ x, const float* __restrict__ W,
    const float* __restrict__ a_src, const float* __restrict__ a_dst,
    float* __restrict__ h, float* __restrict__ as_, float* __restrict__ ad_,
    int blk)
{
    __shared__ float Ws[F * F];
    __shared__ float xs[16][F + 1];
    __shared__ float asv[F], adv[F];

    const int tid = threadIdx.x;
    const int wv  = tid >> 6;
    const int ln  = tid & 63;
    const int q   = ln >> 4;
    const int fl4 = (ln & 15) * 4;
    const int nb  = wv * 4 + q;
    const int node = blk * 16 + nb;

    for (int i = tid * 4; i < F * F; i += 256 * 4)
        *(float4*)&Ws[i] = *(const float4*)&W[i];
    if (tid < F) { asv[tid] = a_src[tid]; adv[tid] = a_dst[tid]; }
    {
        const int n  = tid >> 4;
        const int c4 = (tid & 15) * 4;
        const float4 v = *(const float4*)&x[(blk * 16 + n) * F + c4];
        xs[n][c4] = v.x; xs[n][c4+1] = v.y; xs[n][c4+2] = v.z; xs[n][c4+3] = v.w;
    }
    __syncthreads();

    float4 acc = {0.f, 0.f, 0.f, 0.f};
#pragma unroll
    for (int k = 0; k < F; ++k) {
        const float xv = xs[nb][k];
        const float4 w = *(const float4*)&Ws[k * F + fl4];
        acc.x = fmaf(xv, w.x, acc.x);
        acc.y = fmaf(xv, w.y, acc.y);
        acc.z = fmaf(xv, w.z, acc.z);
        acc.w = fmaf(xv, w.w, acc.w);
    }

    *(float4*)&h[node * F + fl4] = acc;

    float vs = acc.x * asv[fl4] + acc.y * asv[fl4+1]
             + acc.z * asv[fl4+2] + acc.w * asv[fl4+3];
    float vd = acc.x * adv[fl4] + acc.y * adv[fl4+1]
             + acc.z * adv[fl4+2] + acc.w * adv[fl4+3];
#pragma unroll
    for (int off = 1; off < 16; off <<= 1) {
        vs += __shfl_xor(vs, off, 64);
        vd += __shfl_xor(vd, off, 64);
    }
    if ((ln & 15) == 0) { as_[node] = vs; ad_[node] = vd; }
}

// ---------------------------------------------------------------------------
// K1: blocks [0,NBLK): per-bucket edge counts -> btot (LDS pre-aggregated).
//     blocks [NBLK, NBLK+LIN_BLOCKS): layer-1 linear.
// ---------------------------------------------------------------------------
__global__ __launch_bounds__(256) void linear1_count(
    const float* __restrict__ x, const float* __restrict__ W,
    const float* __restrict__ a_src, const float* __restrict__ a_dst,
    float* __restrict__ h, float* __restrict__ as_, float* __restrict__ ad_,
    const int* __restrict__ dst, int* __restrict__ btot)
{
    if (blockIdx.x < NBLK) {
        __shared__ int cnt[NB];
        const int blk = blockIdx.x;
        for (int i = threadIdx.x; i < NB; i += 256) cnt[i] = 0;
        __syncthreads();
        const int base = blk * EPB;
#pragma unroll
        for (int it = 0; it < SITER; ++it) {
            const int e = base + it * 256 + threadIdx.x;
            if (e < ETOT) {
                const int d = (e < NEDGES) ? dst[e] : (e - NEDGES);
                atomicAdd(&cnt[d >> 6], 1);
            }
        }
        __syncthreads();
        for (int i = threadIdx.x; i < NB; i += 256)
            if (cnt[i]) atomicAdd(&btot[i], cnt[i]);
        return;
    }
    linear_body(x, W, a_src, a_dst, h, as_, ad_, blockIdx.x - NBLK);
}

// ---------------------------------------------------------------------------
// K2: exclusive scan of bucket totals -> sbase[NB+1]; init gcur = sbase.
// ---------------------------------------------------------------------------
__global__ __launch_bounds__(1024) void sbase_scan(
    const int* __restrict__ btot, int* __restrict__ sbase, int* __restrict__ gcur)
{
    __shared__ int s[1024];
    const int t = threadIdx.x;
    const int v = (t < NB) ? btot[t] : 0;
    s[t] = v;
    __syncthreads();
    for (int off = 1; off < 1024; off <<= 1) {
        int u = (t >= off) ? s[t - off] : 0;
        __syncthreads();
        s[t] += u;
        __syncthreads();
    }
    if (t < NB) { const int e = s[t] - v; sbase[t] = e; gcur[t] = e; }
    if (t == 0) sbase[NB] = ETOT;
}

// ---------------------------------------------------------------------------
// K3: stage edges grouped by bucket: stg[p] = (d&63)<<16 | src.
// Per-block LDS cursors; one global atomic per (block,bucket) for reservation.
// ---------------------------------------------------------------------------
__global__ __launch_bounds__(256) void stage_edges(
    const int* __restrict__ src, const int* __restrict__ dst,
    int* __restrict__ gcur, unsigned int* __restrict__ stg)
{
    __shared__ int cnt[NB];
    __shared__ int lcur[NB];
    const int blk = blockIdx.x;
    for (int i = threadIdx.x; i < NB; i += 256) cnt[i] = 0;
    __syncthreads();
    const int base = blk * EPB;
#pragma unroll
    for (int it = 0; it < SITER; ++it) {
        const int e = base + it * 256 + threadIdx.x;
        if (e < ETOT) {
            const int d = (e < NEDGES) ? dst[e] : (e - NEDGES);
            atomicAdd(&cnt[d >> 6], 1);
        }
    }
    __syncthreads();
    for (int i = threadIdx.x; i < NB; i += 256)
        lcur[i] = cnt[i] ? atomicAdd(&gcur[i], cnt[i]) : 0;
    __syncthreads();
#pragma unroll
    for (int it = 0; it < SITER; ++it) {
        const int e = base + it * 256 + threadIdx.x;
        if (e < ETOT) {
            int s, d;
            if (e < NEDGES) { s = src[e]; d = dst[e]; }
            else            { s = e - NEDGES; d = s; }
            const int p = atomicAdd(&lcur[d >> 6], 1);
            stg[p] = ((unsigned)(d & 63) << 16) | (unsigned)s;
        }
    }
}

// ---------------------------------------------------------------------------
// K4/K5: per-bucket softmax-aggregate with LDS accumulators.
// MODE 0: epilogue = lrelu(v/z + bias) -> x'  then  x' @ Wn, dots -> hout/as/ad
// MODE 1: epilogue = lrelu(v/z + bias) + resid -> out
// ---------------------------------------------------------------------------
template<int MODE>
__global__ __launch_bounds__(256) void agg_bucket(
    const unsigned int* __restrict__ stg, const int* __restrict__ sbase,
    const float* __restrict__ h, const float* __restrict__ as_,
    const float* __restrict__ ad_, const float* __restrict__ bias,
    const float* __restrict__ Wn, const float* __restrict__ an_s,
    const float* __restrict__ an_d,
    float* __restrict__ hout, float* __restrict__ as_out, float* __restrict__ ad_out,
    const float* __restrict__ resid, float* __restrict__ out)
{
    __shared__ float acc[64][ACC_LD];
    __shared__ float zs[64];
    __shared__ float adv[64];

    const int tid = threadIdx.x;
    const int wv  = tid >> 6;
    const int ln  = tid & 63;
    const int b   = blockIdx.x;
    const int nbase = b << 6;
    const int nr  = (NNODES - nbase < 64) ? (NNODES - nbase) : 64;

    for (int i = tid; i < 64 * ACC_LD; i += 256) (&acc[0][0])[i] = 0.f;
    if (tid < 64) {
        zs[tid]  = 0.f;
        adv[tid] = (tid < nr) ? ad_[nbase + tid] : 0.f;
    }
    __syncthreads();

    const int beg = sbase[b], end = sbase[b + 1];
    for (int cb = beg + wv * 64; cb < end; cb += 256) {
        const int e = cb + ln;
        unsigned pk = 0;
        float ev = 0.f;
        if (e < end) {
            pk = stg[e];
            const float t0 = as_[pk & 0xFFFFu] + adv[pk >> 16];
            const float t  = (t0 > 0.f) ? t0 : 0.2f * t0;
            ev = __expf(t);
            atomicAdd(&zs[pk >> 16], ev);
        }
        const int m = (end - cb < 64) ? (end - cb) : 64;
        if (m == 64) {
#pragma unroll 8
            for (int j = 0; j < 64; ++j) {
                const unsigned pkj = (unsigned)__builtin_amdgcn_readlane((int)pk, j);
                const float evj = __int_as_float(
                    __builtin_amdgcn_readlane(__float_as_int(ev), j));
                const float hv = h[(pkj & 0xFFFFu) * F + ln];
                atomicAdd(&acc[pkj >> 16][ln], evj * hv);
            }
        } else {
            for (int j = 0; j < m; ++j) {
                const unsigned pkj = (unsigned)__builtin_amdgcn_readlane((int)pk, j);
                const float evj = __int_as_float(
                    __builtin_amdgcn_readlane(__float_as_int(ev), j));
                const float hv = h[(pkj & 0xFFFFu) * F + ln];
                atomicAdd(&acc[pkj >> 16][ln], evj * hv);
            }
        }
    }
    __syncthreads();

    if (MODE == 0) {
        // normalize + bias + lrelu(0.01), in place in LDS
        {
            const int n  = tid & 63;
            const int fb = (tid >> 6) << 4;
            const float inv = 1.f / (zs[n] + 1e-16f);
#pragma unroll
            for (int k = 0; k < 16; ++k) {
                float v = acc[n][fb + k] * inv + bias[fb + k];
                acc[n][fb + k] = (v > 0.f) ? v : 0.01f * v;
            }
        }
        __shared__ float Ws[F * F];
        for (int i = tid * 4; i < F * F; i += 1024)
            *(float4*)&Ws[i] = *(const float4*)&Wn[i];
        __syncthreads();

        const int n  = tid >> 2;           // node 0..63
        const int c0 = (tid & 3) << 4;     // 16 output cols
        float4 o0 = {0,0,0,0}, o1 = {0,0,0,0}, o2 = {0,0,0,0}, o3 = {0,0,0,0};
        for (int k = 0; k < F; ++k) {
            const float xv = acc[n][k];
            const float4 w0 = *(const float4*)&Ws[k * F + c0];
            const float4 w1 = *(const float4*)&Ws[k * F + c0 + 4];
            const float4 w2 = *(const float4*)&Ws[k * F + c0 + 8];
            const float4 w3 = *(const float4*)&Ws[k * F + c0 + 12];
            o0.x = fmaf(xv, w0.x, o0.x); o0.y = fmaf(xv, w0.y, o0.y);
            o0.z = fmaf(xv, w0.z, o0.z); o0.w = fmaf(xv, w0.w, o0.w);
            o1.x = fmaf(xv, w1.x, o1.x); o1.y = fmaf(xv, w1.y, o1.y);
            o1.z = fmaf(xv, w1.z, o1.z); o1.w = fmaf(xv, w1.w, o1.w);
            o2.x = fmaf(xv, w2.x, o2.x); o2.y = fmaf(xv, w2.y, o2.y);
            o2.z = fmaf(xv, w2.z, o2.z); o2.w = fmaf(xv, w2.w, o2.w);
            o3.x = fmaf(xv, w3.x, o3.x); o3.y = fmaf(xv, w3.y, o3.y);
            o3.z = fmaf(xv, w3.z, o3.z); o3.w = fmaf(xv, w3.w, o3.w);
        }
        if (n < nr) {
            const int node = nbase + n;
            *(float4*)&hout[node * F + c0]      = o0;
            *(float4*)&hout[node * F + c0 + 4]  = o1;
            *(float4*)&hout[node * F + c0 + 8]  = o2;
            *(float4*)&hout[node * F + c0 + 12] = o3;
            float vs = o0.x*an_s[c0]    + o0.y*an_s[c0+1]  + o0.z*an_s[c0+2]  + o0.w*an_s[c0+3]
                     + o1.x*an_s[c0+4]  + o1.y*an_s[c0+5]  + o1.z*an_s[c0+6]  + o1.w*an_s[c0+7]
                     + o2.x*an_s[c0+8]  + o2.y*an_s[c0+9]  + o2.z*an_s[c0+10] + o2.w*an_s[c0+11]
                     + o3.x*an_s[c0+12] + o3.y*an_s[c0+13] + o3.z*an_s[c0+14] + o3.w*an_s[c0+15];
            float vd = o0.x*an_d[c0]    + o0.y*an_d[c0+1]  + o0.z*an_d[c0+2]  + o0.w*an_d[c0+3]
                     + o1.x*an_d[c0+4]  + o1.y*an_d[c0+5]  + o1.z*an_d[c0+6]  + o1.w*an_d[c0+7]
                     + o2.x*an_d[c0+8]  + o2.y*an_d[c0+9]  + o2.z*an_d[c0+10] + o2.w*an_d[c0+11]
                     + o3.x*an_d[c0+12] + o3.y*an_d[c0+13] + o3.z*an_d[c0+14] + o3.w*an_d[c0+15];
            vs += __shfl_xor(vs, 1, 64); vs += __shfl_xor(vs, 2, 64);
            vd += __shfl_xor(vd, 1, 64); vd += __shfl_xor(vd, 2, 64);
            if ((tid & 3) == 0) { as_out[node] = vs; ad_out[node] = vd; }
        }
    } else {
        const int n  = tid & 63;
        const int fb = (tid >> 6) << 4;
        if (n < nr) {
            const int node = nbase + n;
            const float inv = 1.f / (zs[n] + 1e-16f);
#pragma unroll
            for (int k4 = 0; k4 < 4; ++k4) {
                const int c = fb + k4 * 4;
                float4 v;
                v.x = acc[n][c]     * inv + bias[c];
                v.y = acc[n][c + 1] * inv + bias[c + 1];
                v.z = acc[n][c + 2] * inv + bias[c + 2];
                v.w = acc[n][c + 3] * inv + bias[c + 3];
                v.x = (v.x > 0.f) ? v.x : 0.01f * v.x;
                v.y = (v.y > 0.f) ? v.y : 0.01f * v.y;
                v.z = (v.z > 0.f) ? v.z : 0.01f * v.z;
                v.w = (v.w > 0.f) ? v.w : 0.01f * v.w;
                const float4 r = *(const float4*)&resid[node * F + c];
                v.x += r.x; v.y += r.y; v.z += r.z; v.w += r.w;
                *(float4*)&out[node * F + c] = v;
            }
        }
    }
}

extern "C" void kernel_launch(void* const* d_in, const int* in_sizes, int n_in,
                              void* d_out, int out_size, void* d_ws, size_t ws_size,
                              hipStream_t stream)
{
    const float* x   = (const float*)d_in[0];
    const int*   ei  = (const int*)  d_in[1];   // [2, NEDGES] row-major
    const float* W0  = (const float*)d_in[2];
    const float* as0 = (const float*)d_in[3];
    const float* ad0 = (const float*)d_in[4];
    const float* b0  = (const float*)d_in[5];
    const float* W1  = (const float*)d_in[6];
    const float* as1 = (const float*)d_in[7];
    const float* ad1 = (const float*)d_in[8];
    const float* b1  = (const float*)d_in[9];
    float* out = (float*)d_out;

    const int* src = ei;
    const int* dst = ei + NEDGES;

    // workspace carve-up
    char* ws = (char*)d_ws;
    float* h     = (float*)ws; ws += (size_t)NNODES * F * 4;
    float* hmid  = (float*)ws; ws += (size_t)NNODES * F * 4;
    float* as_   = (float*)ws; ws += (size_t)NNODES * 4;
    float* ad_   = (float*)ws; ws += (size_t)NNODES * 4;
    float* as2   = (float*)ws; ws += (size_t)NNODES * 4;
    float* ad2   = (float*)ws; ws += (size_t)NNODES * 4;
    int*   btot  = (int*)ws;   ws += (size_t)NB * 4;
    int*   sbase = (int*)ws;   ws += (size_t)(NB + 1) * 4;
    int*   gcur  = (int*)ws;   ws += (size_t)NB * 4;
    unsigned int* stg = (unsigned int*)ws; ws += (size_t)ETOT * 4;

    hipMemsetAsync(btot, 0, (size_t)NB * 4, stream);
    linear1_count<<<NBLK + LIN_BLOCKS, 256, 0, stream>>>(
        x, W0, as0, ad0, h, as_, ad_, dst, btot);
    sbase_scan<<<1, 1024, 0, stream>>>(btot, sbase, gcur);
    stage_edges<<<NBLK, 256, 0, stream>>>(src, dst, gcur, stg);

    // layer-1 aggregate + fused layer-2 linear
    agg_bucket<0><<<NB, 256, 0, stream>>>(stg, sbase, h, as_, ad_, b0,
                                          W1, as1, ad1, hmid, as2, ad2,
                                          nullptr, nullptr);
    // layer-2 aggregate + residual
    agg_bucket<1><<<NB, 256, 0, stream>>>(stg, sbase, hmid, as2, ad2, b1,
                                          nullptr, nullptr, nullptr,
                                          nullptr, nullptr, nullptr,
                                          x, out);
}

// Round 5
// 232.216 us; speedup vs baseline: 3.7874x; 3.7874x over previous
//
#include <hip/hip_runtime.h>
#include <math.h>

#define NNODES 50000
#define NEDGES 800000
#define ETOT   850000            // edges + self loops
#define F      64
#define NB     782               // ceil(NNODES/64) buckets of 64 nodes
#define SCAN_BLOCKS 196
#define LIN_BLOCKS  3125         // 16 nodes / block
#define HIST_BLOCKS 3321         // ceil(ETOT/256)
#define AGG_BLOCKS  12500        // 4 nodes / block (wave per node)
#define SBLK   128               // staging blocks
#define SIT    26                // edges/thread in staging
#define SEPB   (256 * SIT)       // 6656 edges per staging block

typedef unsigned short u16;
typedef unsigned int   u32;

// pack two f32 -> two bf16 (RNE)
__device__ __forceinline__ u32 f2bf2(float a, float b) {
    u32 ua = __float_as_uint(a), ub = __float_as_uint(b);
    ua = (ua + 0x7FFFu + ((ua >> 16) & 1u)) >> 16;
    ub = (ub + 0x7FFFu + ((ub >> 16) & 1u)) >> 16;
    return ua | (ub << 16);
}

__device__ __forceinline__ float4 load4f(const float* p) { return *(const float4*)p; }
__device__ __forceinline__ float4 load4f(const u16* p) {
    uint2 u = *(const uint2*)p;
    float4 v;
    v.x = __uint_as_float(u.x << 16); v.y = __uint_as_float(u.x & 0xFFFF0000u);
    v.z = __uint_as_float(u.y << 16); v.w = __uint_as_float(u.y & 0xFFFF0000u);
    return v;
}

// ---------------------------------------------------------------------------
// Linear body: h16 = bf16(x @ W) ; as_ = (xW).a_src ; ad_ = (xW).a_dst
// 16 nodes / block; quarter-wave (16 lanes) per node, 4 output cols per lane.
// ---------------------------------------------------------------------------
template <typename TIN>
__device__ __forceinline__ void linear_body(
    const TIN* __restrict__ x, const float* __restrict__ W,
    const float* __restrict__ a_src, const float* __restrict__ a_dst,
    u16* __restrict__ h16, float* __restrict__ as_, float* __restrict__ ad_,
    int blk)
{
    __shared__ float Ws[F * F];
    __shared__ float xs[16][F + 1];
    __shared__ float asv[F], adv[F];

    const int tid = threadIdx.x;
    const int wv  = tid >> 6;
    const int ln  = tid & 63;
    const int q   = ln >> 4;
    const int fl4 = (ln & 15) * 4;
    const int nb  = wv * 4 + q;
    const int node = blk * 16 + nb;

    for (int i = tid * 4; i < F * F; i += 1024)
        *(float4*)&Ws[i] = *(const float4*)&W[i];
    if (tid < F) { asv[tid] = a_src[tid]; adv[tid] = a_dst[tid]; }
    {
        const int n  = tid >> 4;
        const int c4 = (tid & 15) * 4;
        const float4 v = load4f(&x[(size_t)(blk * 16 + n) * F + c4]);
        xs[n][c4] = v.x; xs[n][c4+1] = v.y; xs[n][c4+2] = v.z; xs[n][c4+3] = v.w;
    }
    __syncthreads();

    float4 acc = {0.f, 0.f, 0.f, 0.f};
#pragma unroll
    for (int k = 0; k < F; ++k) {
        const float xv = xs[nb][k];
        const float4 w = *(const float4*)&Ws[k * F + fl4];
        acc.x = fmaf(xv, w.x, acc.x);
        acc.y = fmaf(xv, w.y, acc.y);
        acc.z = fmaf(xv, w.z, acc.z);
        acc.w = fmaf(xv, w.w, acc.w);
    }

    uint2 p;
    p.x = f2bf2(acc.x, acc.y);
    p.y = f2bf2(acc.z, acc.w);
    *(uint2*)(h16 + (size_t)node * F + fl4) = p;

    float vs = acc.x * asv[fl4] + acc.y * asv[fl4+1]
             + acc.z * asv[fl4+2] + acc.w * asv[fl4+3];
    float vd = acc.x * adv[fl4] + acc.y * adv[fl4+1]
             + acc.z * adv[fl4+2] + acc.w * adv[fl4+3];
#pragma unroll
    for (int off = 1; off < 16; off <<= 1) {
        vs += __shfl_xor(vs, off, 64);
        vd += __shfl_xor(vd, off, 64);
    }
    if ((ln & 15) == 0) { as_[node] = vs; ad_[node] = vd; }
}

// K1: layer-1 linear fused with per-node dst histogram.
__global__ __launch_bounds__(256) void linear1_hist(
    const float* __restrict__ x, const float* __restrict__ W,
    const float* __restrict__ a_src, const float* __restrict__ a_dst,
    u16* __restrict__ h16, float* __restrict__ as_, float* __restrict__ ad_,
    const int* __restrict__ dst, int* __restrict__ cnt)
{
    if (blockIdx.x >= LIN_BLOCKS) {
        const int e = (blockIdx.x - LIN_BLOCKS) * 256 + threadIdx.x;
        if (e < ETOT) {
            const int d = (e < NEDGES) ? dst[e] : (e - NEDGES);
            atomicAdd(&cnt[d], 1);
        }
        return;
    }
    linear_body<float>(x, W, a_src, a_dst, h16, as_, ad_, blockIdx.x);
}

// layer-2 linear: bf16 input
__global__ __launch_bounds__(256) void node_linear2(
    const u16* __restrict__ x, const float* __restrict__ W,
    const float* __restrict__ a_src, const float* __restrict__ a_dst,
    u16* __restrict__ h16, float* __restrict__ as_, float* __restrict__ ad_)
{
    linear_body<u16>(x, W, a_src, a_dst, h16, as_, ad_, blockIdx.x);
}

// ---------------------------------------------------------------------------
// Per-node exclusive scan -> rowptr; gcur seeded at bucket starts.
// ---------------------------------------------------------------------------
__global__ __launch_bounds__(256) void scan1(
    const int* __restrict__ cnt, int* __restrict__ rowptr, int* __restrict__ bsum)
{
    __shared__ int s[256];
    const int i = blockIdx.x * 256 + threadIdx.x;
    const int v = (i < NNODES) ? cnt[i] : 0;
    s[threadIdx.x] = v;
    __syncthreads();
    for (int off = 1; off < 256; off <<= 1) {
        int t = (threadIdx.x >= off) ? s[threadIdx.x - off] : 0;
        __syncthreads();
        s[threadIdx.x] += t;
        __syncthreads();
    }
    if (i < NNODES) rowptr[i] = s[threadIdx.x] - v;
    if (threadIdx.x == 255) bsum[blockIdx.x] = s[255];
}

__global__ __launch_bounds__(256) void scan2(int* __restrict__ bsum)
{
    __shared__ int s[256];
    const int v = (threadIdx.x < SCAN_BLOCKS) ? bsum[threadIdx.x] : 0;
    s[threadIdx.x] = v;
    __syncthreads();
    for (int off = 1; off < 256; off <<= 1) {
        int t = (threadIdx.x >= off) ? s[threadIdx.x - off] : 0;
        __syncthreads();
        s[threadIdx.x] += t;
        __syncthreads();
    }
    if (threadIdx.x < SCAN_BLOCKS) bsum[threadIdx.x] = s[threadIdx.x] - v;
}

__global__ __launch_bounds__(256) void scan3(
    int* __restrict__ rowptr, const int* __restrict__ bsum, int* __restrict__ gcur)
{
    const int i = blockIdx.x * 256 + threadIdx.x;
    if (i < NNODES) {
        const int r = rowptr[i] + bsum[blockIdx.x];
        rowptr[i] = r;
        if ((i & 63) == 0) gcur[i >> 6] = r;   // bucket segment base
    }
    if (i == 0) rowptr[NNODES] = ETOT;
}

// ---------------------------------------------------------------------------
// Stage A: group edges by 64-node bucket. Packed entry (d&63)<<16 | src.
// LDS counts per bucket; ONE global reservation per (block,bucket) ->
// contiguous ~34B runs instead of random 4B writes.
// ---------------------------------------------------------------------------
__global__ __launch_bounds__(256) void stage_edges(
    const int* __restrict__ src, const int* __restrict__ dst,
    int* __restrict__ gcur, u32* __restrict__ stg)
{
    __shared__ int cnt[NB];
    __shared__ int lcur[NB];
    for (int i = threadIdx.x; i < NB; i += 256) cnt[i] = 0;
    __syncthreads();
    const int base = blockIdx.x * SEPB;
#pragma unroll
    for (int it = 0; it < SIT; ++it) {
        const int e = base + it * 256 + threadIdx.x;
        if (e < ETOT) {
            const int d = (e < NEDGES) ? dst[e] : (e - NEDGES);
            atomicAdd(&cnt[d >> 6], 1);
        }
    }
    __syncthreads();
    for (int i = threadIdx.x; i < NB; i += 256)
        lcur[i] = cnt[i] ? atomicAdd(&gcur[i], cnt[i]) : 0;
    __syncthreads();
#pragma unroll
    for (int it = 0; it < SIT; ++it) {
        const int e = base + it * 256 + threadIdx.x;
        if (e < ETOT) {
            int s, d;
            if (e < NEDGES) { s = src[e]; d = dst[e]; }
            else            { s = e - NEDGES; d = s; }
            const int p = atomicAdd(&lcur[d >> 6], 1);
            stg[p] = ((u32)(d & 63) << 16) | (u32)s;
        }
    }
}

// ---------------------------------------------------------------------------
// Stage B: within each bucket, scatter to exact per-node CSR slots.
// Dense reads (bucket segment), dense u16 writes (~2.2KB region), LDS int
// cursors (native ds_add).
// ---------------------------------------------------------------------------
__global__ __launch_bounds__(256) void bucket_csr(
    const int* __restrict__ rowptr, const u32* __restrict__ stg,
    u16* __restrict__ csr)
{
    __shared__ int lcur[64];
    const int b = blockIdx.x;
    const int nbase = b << 6;
    if (threadIdx.x < 64) {
        const int node = nbase + threadIdx.x;
        lcur[threadIdx.x] = (node < NNODES) ? rowptr[node] : 0;
    }
    __syncthreads();
    const int endn = (nbase + 64 < NNODES) ? (nbase + 64) : NNODES;
    const int beg = rowptr[nbase];
    const int end = rowptr[endn];
    for (int i = beg + threadIdx.x; i < end; i += 256) {
        const u32 pk = stg[i];
        const int pos = atomicAdd(&lcur[pk >> 16], 1);
        csr[pos] = (u16)(pk & 0xFFFFu);
    }
}

// ---------------------------------------------------------------------------
// Fused softmax + aggregate + bias + LeakyReLU(0.01).
// Wave per node; 8 lanes per edge (8 bf16 features / lane) -> 8 edges in
// flight per wave. MODE 0: write bf16 hmid. MODE 1: +residual, write f32 out.
// ---------------------------------------------------------------------------
template<int MODE>
__global__ __launch_bounds__(256) void gat_agg(
    const int* __restrict__ rowptr, const u16* __restrict__ csr,
    const u16* __restrict__ h16, const float* __restrict__ as_,
    const float* __restrict__ ad_, const float* __restrict__ bias,
    u16* __restrict__ hout16,
    const float* __restrict__ resid, float* __restrict__ out)
{
    const int tid  = threadIdx.x;
    const int wv   = tid >> 6;
    const int ln   = tid & 63;
    const int node = blockIdx.x * 4 + wv;
    const int g    = ln >> 3;      // edge slot 0..7
    const int l    = ln & 7;       // 16B chunk of the 128B bf16 row

    const float ad_n = ad_[node];
    const int beg = rowptr[node];
    const int end = rowptr[node + 1];

    float a0=0.f,a1=0.f,a2=0.f,a3=0.f,a4=0.f,a5=0.f,a6=0.f,a7=0.f;
    float z = 0.f;
    for (int i = beg + g; i < end; i += 8) {
        const int s = csr[i];
        float t = as_[s] + ad_n;
        t = (t > 0.f) ? t : 0.2f * t;
        const float ev = __expf(t);
        const uint4 hv = ((const uint4*)(h16 + (size_t)s * F))[l];
        z += ev;
        a0 = fmaf(ev, __uint_as_float(hv.x << 16),          a0);
        a1 = fmaf(ev, __uint_as_float(hv.x & 0xFFFF0000u),  a1);
        a2 = fmaf(ev, __uint_as_float(hv.y << 16),          a2);
        a3 = fmaf(ev, __uint_as_float(hv.y & 0xFFFF0000u),  a3);
        a4 = fmaf(ev, __uint_as_float(hv.z << 16),          a4);
        a5 = fmaf(ev, __uint_as_float(hv.z & 0xFFFF0000u),  a5);
        a6 = fmaf(ev, __uint_as_float(hv.w << 16),          a6);
        a7 = fmaf(ev, __uint_as_float(hv.w & 0xFFFF0000u),  a7);
    }
#pragma unroll
    for (int off = 8; off < 64; off <<= 1) {
        a0 += __shfl_xor(a0, off, 64); a1 += __shfl_xor(a1, off, 64);
        a2 += __shfl_xor(a2, off, 64); a3 += __shfl_xor(a3, off, 64);
        a4 += __shfl_xor(a4, off, 64); a5 += __shfl_xor(a5, off, 64);
        a6 += __shfl_xor(a6, off, 64); a7 += __shfl_xor(a7, off, 64);
        z  += __shfl_xor(z,  off, 64);
    }

    if (g == 0) {
        const float inv = 1.f / (z + 1e-16f);
        const float4 b0 = *(const float4*)&bias[l * 8];
        const float4 b1 = *(const float4*)&bias[l * 8 + 4];
        float v0 = a0 * inv + b0.x, v1 = a1 * inv + b0.y;
        float v2 = a2 * inv + b0.z, v3 = a3 * inv + b0.w;
        float v4 = a4 * inv + b1.x, v5 = a5 * inv + b1.y;
        float v6 = a6 * inv + b1.z, v7 = a7 * inv + b1.w;
        v0 = (v0 > 0.f) ? v0 : 0.01f * v0;  v1 = (v1 > 0.f) ? v1 : 0.01f * v1;
        v2 = (v2 > 0.f) ? v2 : 0.01f * v2;  v3 = (v3 > 0.f) ? v3 : 0.01f * v3;
        v4 = (v4 > 0.f) ? v4 : 0.01f * v4;  v5 = (v5 > 0.f) ? v5 : 0.01f * v5;
        v6 = (v6 > 0.f) ? v6 : 0.01f * v6;  v7 = (v7 > 0.f) ? v7 : 0.01f * v7;
        if (MODE == 0) {
            uint4 p;
            p.x = f2bf2(v0, v1); p.y = f2bf2(v2, v3);
            p.z = f2bf2(v4, v5); p.w = f2bf2(v6, v7);
            ((uint4*)(hout16 + (size_t)node * F))[l] = p;
        } else {
            const float4 r0 = *(const float4*)(resid + (size_t)node * F + l * 8);
            const float4 r1 = *(const float4*)(resid + (size_t)node * F + l * 8 + 4);
            float4 o0, o1;
            o0.x = v0 + r0.x; o0.y = v1 + r0.y; o0.z = v2 + r0.z; o0.w = v3 + r0.w;
            o1.x = v4 + r1.x; o1.y = v5 + r1.y; o1.z = v6 + r1.z; o1.w = v7 + r1.w;
            *(float4*)(out + (size_t)node * F + l * 8)     = o0;
            *(float4*)(out + (size_t)node * F + l * 8 + 4) = o1;
        }
    }
}

extern "C" void kernel_launch(void* const* d_in, const int* in_sizes, int n_in,
                              void* d_out, int out_size, void* d_ws, size_t ws_size,
                              hipStream_t stream)
{
    const float* x   = (const float*)d_in[0];
    const int*   ei  = (const int*)  d_in[1];   // [2, NEDGES] row-major
    const float* W0  = (const float*)d_in[2];
    const float* as0 = (const float*)d_in[3];
    const float* ad0 = (const float*)d_in[4];
    const float* b0  = (const float*)d_in[5];
    const float* W1  = (const float*)d_in[6];
    const float* as1 = (const float*)d_in[7];
    const float* ad1 = (const float*)d_in[8];
    const float* b1  = (const float*)d_in[9];
    float* out = (float*)d_out;

    const int* src = ei;
    const int* dst = ei + NEDGES;

    // workspace carve-up (~19 MB)
    char* ws = (char*)d_ws;
    u16*   h16    = (u16*)ws;   ws += (size_t)NNODES * F * 2;   // layer h (bf16), reused L2
    u16*   hmid16 = (u16*)ws;   ws += (size_t)NNODES * F * 2;   // layer-1 output (bf16)
    float* as_    = (float*)ws; ws += (size_t)NNODES * 4;
    float* ad_    = (float*)ws; ws += (size_t)NNODES * 4;
    float* as2    = (float*)ws; ws += (size_t)NNODES * 4;
    float* ad2    = (float*)ws; ws += (size_t)NNODES * 4;
    int*   cnt    = (int*)ws;   ws += (size_t)NNODES * 4;
    int*   rowptr = (int*)ws;   ws += (size_t)(NNODES + 1) * 4;
    int*   bsum   = (int*)ws;   ws += (size_t)SCAN_BLOCKS * 4;
    int*   gcur   = (int*)ws;   ws += (size_t)NB * 4;
    u32*   stg    = (u32*)ws;   ws += (size_t)ETOT * 4;
    u16*   csr    = (u16*)ws;   ws += (size_t)ETOT * 2;

    hipMemsetAsync(cnt, 0, (size_t)NNODES * 4, stream);
    linear1_hist<<<LIN_BLOCKS + HIST_BLOCKS, 256, 0, stream>>>(
        x, W0, as0, ad0, h16, as_, ad_, dst, cnt);
    scan1<<<SCAN_BLOCKS, 256, 0, stream>>>(cnt, rowptr, bsum);
    scan2<<<1, 256, 0, stream>>>(bsum);
    scan3<<<SCAN_BLOCKS, 256, 0, stream>>>(rowptr, bsum, gcur);
    stage_edges<<<SBLK, 256, 0, stream>>>(src, dst, gcur, stg);
    bucket_csr<<<NB, 256, 0, stream>>>(rowptr, stg, csr);

    // layer 1 aggregate -> bf16 hmid
    gat_agg<0><<<AGG_BLOCKS, 256, 0, stream>>>(rowptr, csr, h16, as_, ad_,
                                               b0, hmid16, nullptr, nullptr);
    // layer 2 linear (bf16 in, bf16 h out) -- h16 safely reused (prev reader done)
    node_linear2<<<LIN_BLOCKS, 256, 0, stream>>>(hmid16, W1, as1, ad1, h16, as2, ad2);
    // layer 2 aggregate + residual -> out
    gat_agg<1><<<AGG_BLOCKS, 256, 0, stream>>>(rowptr, csr, h16, as2, ad2,
                                               b1, nullptr, x, out);
}